// Round 1
// baseline (10859.159 us; speedup 1.0000x reference)
//
#include <hip/hip_runtime.h>

#define N_NODES 100000
#define N_EDGES 3200000
#define D 256

// ---------------------------------------------------------------------------
// Stage 1: SpMM  AX = A_coo @ X   via fp32 atomics. One wave per edge.
// Lane l handles features [4l, 4l+4): gather float4 from X[col], scale, scatter.
// ---------------------------------------------------------------------------
__global__ __launch_bounds__(256) void spmm_atomic(
    const float* __restrict__ X,
    const int* __restrict__ rows,
    const int* __restrict__ cols,
    const float* __restrict__ vals,
    float* __restrict__ AX,
    int nEdges)
{
    int wave = (int)((blockIdx.x * (unsigned)blockDim.x + threadIdx.x) >> 6);
    int lane = threadIdx.x & 63;
    if (wave >= nEdges) return;
    int row = rows[wave];
    int col = cols[wave];
    float val = vals[wave];
    const float4* xs = (const float4*)(X + (size_t)col * D);
    float4 v = xs[lane];
    float* dst = AX + (size_t)row * D + lane * 4;
    atomicAdd(dst + 0, v.x * val);
    atomicAdd(dst + 1, v.y * val);
    atomicAdd(dst + 2, v.z * val);
    atomicAdd(dst + 3, v.w * val);
}

// ---------------------------------------------------------------------------
// Stage 2: H = relu(AX @ W^T).  W is [D_out, D_in] row-major.
// Classic fp32 LDS-tiled GEMM: 64x64 tile, BK=32, 256 threads, 4x4 microtile.
// ---------------------------------------------------------------------------
__global__ __launch_bounds__(256) void gemm_relu(
    const float* __restrict__ A,   // [M, 256]  (= AX)
    const float* __restrict__ W,   // [256, 256] row-major [out, in]
    float* __restrict__ H,         // [M, 256]
    int M)
{
    __shared__ float As[64][33];   // +1 pad vs bank conflicts
    __shared__ float Bs[32][65];   // Bs[k][n] = W[n0+n][k0+k]
    const int t  = threadIdx.x;
    const int m0 = blockIdx.x * 64;
    const int n0 = blockIdx.y * 64;
    const int tx = t & 15, ty = t >> 4;

    float acc[4][4] = {};

    for (int k0 = 0; k0 < 256; k0 += 32) {
        // Load A tile: 64 rows x 32 cols = 512 float4 / 256 threads = 2 each
        #pragma unroll
        for (int i = 0; i < 2; ++i) {
            int flat = t + i * 256;          // 0..511
            int r = flat >> 3;
            int c4 = (flat & 7) * 4;
            float4 a = make_float4(0.f, 0.f, 0.f, 0.f);
            if (m0 + r < M)
                a = *(const float4*)(A + (size_t)(m0 + r) * 256 + k0 + c4);
            As[r][c4 + 0] = a.x; As[r][c4 + 1] = a.y;
            As[r][c4 + 2] = a.z; As[r][c4 + 3] = a.w;
        }
        // Load B tile (transpose W on the fly). n0+n < 256 always (N=256 exact).
        #pragma unroll
        for (int i = 0; i < 2; ++i) {
            int flat = t + i * 256;
            int n = flat >> 3;
            int k4 = (flat & 7) * 4;
            float4 w = *(const float4*)(W + (size_t)(n0 + n) * 256 + k0 + k4);
            Bs[k4 + 0][n] = w.x; Bs[k4 + 1][n] = w.y;
            Bs[k4 + 2][n] = w.z; Bs[k4 + 3][n] = w.w;
        }
        __syncthreads();

        #pragma unroll
        for (int k = 0; k < 32; ++k) {
            float a[4], b[4];
            #pragma unroll
            for (int i = 0; i < 4; ++i) a[i] = As[ty * 4 + i][k];
            #pragma unroll
            for (int j = 0; j < 4; ++j) b[j] = Bs[k][tx * 4 + j];
            #pragma unroll
            for (int i = 0; i < 4; ++i)
                #pragma unroll
                for (int j = 0; j < 4; ++j)
                    acc[i][j] += a[i] * b[j];
        }
        __syncthreads();
    }

    #pragma unroll
    for (int i = 0; i < 4; ++i) {
        int m = m0 + ty * 4 + i;
        if (m < M) {
            #pragma unroll
            for (int j = 0; j < 4; ++j) {
                float v = acc[i][j];
                H[(size_t)m * 256 + n0 + tx * 4 + j] = v > 0.f ? v : 0.f;
            }
        }
    }
}

extern "C" void kernel_launch(void* const* d_in, const int* in_sizes, int n_in,
                              void* d_out, int out_size, void* d_ws, size_t ws_size,
                              hipStream_t stream) {
    const float* X    = (const float*)d_in[0];
    const int*   rows = (const int*)d_in[1];
    const int*   cols = (const int*)d_in[2];
    const float* vals = (const float*)d_in[3];
    const float* W    = (const float*)d_in[4];
    float*       H    = (float*)d_out;
    float*       AX   = (float*)d_ws;   // 100000*256*4 = 102.4 MB scratch

    hipMemsetAsync(AX, 0, (size_t)N_NODES * D * sizeof(float), stream);

    // One wave per edge: 3.2M waves -> 800000 blocks of 256 threads (4 waves).
    int blocks = (N_EDGES + 3) / 4;
    spmm_atomic<<<blocks, 256, 0, stream>>>(X, rows, cols, vals, AX, N_EDGES);

    dim3 g((N_NODES + 63) / 64, 256 / 64);
    gemm_relu<<<g, 256, 0, stream>>>(AX, W, H, N_NODES);
}

// Round 2
// 1108.710 us; speedup vs baseline: 9.7944x; 9.7944x over previous
//
#include <hip/hip_runtime.h>

#define N_NODES 100000
#define N_EDGES 3200000
#define D 256

// ============================ CSR construction =============================

__global__ __launch_bounds__(256) void edge_histogram(
    const int* __restrict__ rows, int* __restrict__ cnt, int nEdges)
{
    int e = blockIdx.x * 256 + threadIdx.x;
    if (e < nEdges) atomicAdd(&cnt[rows[e]], 1);
}

// Single-block chunked exclusive scan: cnt -> row_ptr, cursor.
// NOTE: cnt may alias cursor (each index is read by exactly the thread that
// later writes it, reads complete before writes within the chunk).
__global__ __launch_bounds__(1024) void scan_rowptr(
    const int* __restrict__ cnt, int* __restrict__ row_ptr, int* __restrict__ cursor)
{
    __shared__ int lds[1024];
    __shared__ int carry_s;
    const int t = threadIdx.x;
    if (t == 0) carry_s = 0;
    __syncthreads();
    for (int base = 0; base < N_NODES; base += 4096) {
        int i0 = base + t * 4;
        int x0 = 0, x1 = 0, x2 = 0, x3 = 0;
        if (i0 + 3 < N_NODES) {
            int4 q = *(const int4*)(cnt + i0);
            x0 = q.x; x1 = q.y; x2 = q.z; x3 = q.w;
        } else {
            if (i0     < N_NODES) x0 = cnt[i0];
            if (i0 + 1 < N_NODES) x1 = cnt[i0 + 1];
            if (i0 + 2 < N_NODES) x2 = cnt[i0 + 2];
        }
        int s = x0 + x1 + x2 + x3;
        lds[t] = s;
        __syncthreads();
        for (int off = 1; off < 1024; off <<= 1) {
            int v    = (t >= off) ? lds[t - off] : 0;
            int mine = lds[t];
            __syncthreads();
            lds[t] = mine + v;
            __syncthreads();
        }
        int incl  = lds[t];
        int carry = carry_s;
        int total = lds[1023];
        int e0 = carry + incl - s;          // exclusive prefix for this thread's 4
        __syncthreads();
        if (t == 0) carry_s = carry + total;
        if (i0     < N_NODES) { row_ptr[i0]     = e0;            cursor[i0]     = e0; }
        if (i0 + 1 < N_NODES) { row_ptr[i0 + 1] = e0 + x0;       cursor[i0 + 1] = e0 + x0; }
        if (i0 + 2 < N_NODES) { row_ptr[i0 + 2] = e0 + x0 + x1;  cursor[i0 + 2] = e0 + x0 + x1; }
        if (i0 + 3 < N_NODES) { row_ptr[i0 + 3] = e0 + x0 + x1 + x2;
                                cursor[i0 + 3] = e0 + x0 + x1 + x2; }
        __syncthreads();
    }
    if (t == 0) row_ptr[N_NODES] = carry_s;
}

__global__ __launch_bounds__(256) void edge_scatter(
    const int* __restrict__ rows, const int* __restrict__ cols,
    const float* __restrict__ vals, int* __restrict__ cursor,
    int* __restrict__ ccol, float* __restrict__ cval, int nEdges)
{
    int e = blockIdx.x * 256 + threadIdx.x;
    if (e >= nEdges) return;
    int p = atomicAdd(&cursor[rows[e]], 1);
    ccol[p] = cols[e];
    cval[p] = vals[e];
}

// ======================= Dense GEMM  Y/H = X @ W^T =========================
// 64x64 tile, BK=32, 256 threads, 4x4 microtile. RELU templated.
template<bool RELU>
__global__ __launch_bounds__(256) void gemm_xwt(
    const float* __restrict__ A,   // [M, 256]
    const float* __restrict__ W,   // [256, 256] row-major [out, in]
    float* __restrict__ O,         // [M, 256]
    int M)
{
    __shared__ float As[64][33];
    __shared__ float Bs[32][65];
    const int t  = threadIdx.x;
    const int m0 = blockIdx.x * 64;
    const int n0 = blockIdx.y * 64;
    const int tx = t & 15, ty = t >> 4;

    float acc[4][4] = {};

    for (int k0 = 0; k0 < 256; k0 += 32) {
        #pragma unroll
        for (int i = 0; i < 2; ++i) {
            int flat = t + i * 256;
            int r  = flat >> 3;
            int c4 = (flat & 7) * 4;
            float4 a = make_float4(0.f, 0.f, 0.f, 0.f);
            if (m0 + r < M)
                a = *(const float4*)(A + (size_t)(m0 + r) * 256 + k0 + c4);
            As[r][c4 + 0] = a.x; As[r][c4 + 1] = a.y;
            As[r][c4 + 2] = a.z; As[r][c4 + 3] = a.w;
        }
        #pragma unroll
        for (int i = 0; i < 2; ++i) {
            int flat = t + i * 256;
            int n  = flat >> 3;
            int k4 = (flat & 7) * 4;
            float4 w = *(const float4*)(W + (size_t)(n0 + n) * 256 + k0 + k4);
            Bs[k4 + 0][n] = w.x; Bs[k4 + 1][n] = w.y;
            Bs[k4 + 2][n] = w.z; Bs[k4 + 3][n] = w.w;
        }
        __syncthreads();
        #pragma unroll
        for (int k = 0; k < 32; ++k) {
            float a[4], b[4];
            #pragma unroll
            for (int i = 0; i < 4; ++i) a[i] = As[ty * 4 + i][k];
            #pragma unroll
            for (int j = 0; j < 4; ++j) b[j] = Bs[k][tx * 4 + j];
            #pragma unroll
            for (int i = 0; i < 4; ++i)
                #pragma unroll
                for (int j = 0; j < 4; ++j)
                    acc[i][j] += a[i] * b[j];
        }
        __syncthreads();
    }

    #pragma unroll
    for (int i = 0; i < 4; ++i) {
        int m = m0 + ty * 4 + i;
        if (m < M) {
            #pragma unroll
            for (int j = 0; j < 4; ++j) {
                float v = acc[i][j];
                if (RELU) v = v > 0.f ? v : 0.f;
                O[(size_t)m * 256 + n0 + tx * 4 + j] = v;
            }
        }
    }
}

// ==================== Gather SpMM:  H = relu(A @ Y) ========================
// One wave per row. Lane l owns features [4l, 4l+4).
__global__ __launch_bounds__(256) void spmm_gather_relu(
    const float* __restrict__ Y,
    const int* __restrict__ row_ptr,
    const int* __restrict__ ccol,
    const float* __restrict__ cval,
    float* __restrict__ H)
{
    int row  = blockIdx.x * 4 + (threadIdx.x >> 6);
    int lane = threadIdx.x & 63;
    if (row >= N_NODES) return;
    int s = row_ptr[row];
    int e = row_ptr[row + 1];

    float4 acc = make_float4(0.f, 0.f, 0.f, 0.f);
    for (int base = s; base < e; base += 64) {
        int idx = base + lane;
        int   c = 0;
        float v = 0.f;
        if (idx < e) { c = ccol[idx]; v = cval[idx]; }
        int cnt = min(64, e - base);
        for (int j = 0; j < cnt; ++j) {
            int   cj = __shfl(c, j);
            float vj = __shfl(v, j);
            float4 y = ((const float4*)(Y + (size_t)cj * 256))[lane];
            acc.x += y.x * vj; acc.y += y.y * vj;
            acc.z += y.z * vj; acc.w += y.w * vj;
        }
    }
    float4 r;
    r.x = acc.x > 0.f ? acc.x : 0.f;
    r.y = acc.y > 0.f ? acc.y : 0.f;
    r.z = acc.z > 0.f ? acc.z : 0.f;
    r.w = acc.w > 0.f ? acc.w : 0.f;
    ((float4*)(H + (size_t)row * 256))[lane] = r;
}

// ==================== Fallback (R1): atomic scatter SpMM ===================
__global__ __launch_bounds__(256) void spmm_atomic(
    const float* __restrict__ X,
    const int* __restrict__ rows,
    const int* __restrict__ cols,
    const float* __restrict__ vals,
    float* __restrict__ AX,
    int nEdges)
{
    int wave = (int)((blockIdx.x * (unsigned)blockDim.x + threadIdx.x) >> 6);
    int lane = threadIdx.x & 63;
    if (wave >= nEdges) return;
    int row = rows[wave];
    int col = cols[wave];
    float val = vals[wave];
    float4 v = ((const float4*)(X + (size_t)col * D))[lane];
    float* dst = AX + (size_t)row * D + lane * 4;
    atomicAdd(dst + 0, v.x * val);
    atomicAdd(dst + 1, v.y * val);
    atomicAdd(dst + 2, v.z * val);
    atomicAdd(dst + 3, v.w * val);
}

// ===========================================================================

extern "C" void kernel_launch(void* const* d_in, const int* in_sizes, int n_in,
                              void* d_out, int out_size, void* d_ws, size_t ws_size,
                              hipStream_t stream) {
    const float* X    = (const float*)d_in[0];
    const int*   rows = (const int*)d_in[1];
    const int*   cols = (const int*)d_in[2];
    const float* vals = (const float*)d_in[3];
    const float* W    = (const float*)d_in[4];
    float*       H    = (float*)d_out;

    const size_t Y_BYTES  = (size_t)N_NODES * D * sizeof(float); // 102,400,000
    const size_t RP_BYTES = 400384;                              // (N+1)*4 padded
    const size_t CE_BYTES = (size_t)N_EDGES * 4;                 // 12,800,000
    const size_t NEEDED   = Y_BYTES + 2 * RP_BYTES + 2 * CE_BYTES;

    char* ws = (char*)d_ws;

    if (ws_size >= NEEDED) {
        float* Y       = (float*)(ws);
        int*   row_ptr = (int*)  (ws + Y_BYTES);
        int*   cursor  = (int*)  (ws + Y_BYTES + RP_BYTES);   // also histogram cnt
        int*   ccol    = (int*)  (ws + Y_BYTES + 2 * RP_BYTES);
        float* cval    = (float*)(ws + Y_BYTES + 2 * RP_BYTES + CE_BYTES);

        hipMemsetAsync(cursor, 0, (size_t)N_NODES * sizeof(int), stream);

        int eb = (N_EDGES + 255) / 256;
        edge_histogram<<<eb, 256, 0, stream>>>(rows, cursor, N_EDGES);
        scan_rowptr<<<1, 1024, 0, stream>>>(cursor, row_ptr, cursor);
        edge_scatter<<<eb, 256, 0, stream>>>(rows, cols, vals, cursor, ccol, cval, N_EDGES);

        dim3 g((N_NODES + 63) / 64, 256 / 64);
        gemm_xwt<false><<<g, 256, 0, stream>>>(X, W, Y, N_NODES);

        spmm_gather_relu<<<(N_NODES + 3) / 4, 256, 0, stream>>>(Y, row_ptr, ccol, cval, H);
    } else {
        // Fallback: R1 path (atomic scatter + fused GEMM-ReLU)
        float* AX = (float*)d_ws;
        hipMemsetAsync(AX, 0, Y_BYTES, stream);
        int blocks = (N_EDGES + 3) / 4;
        spmm_atomic<<<blocks, 256, 0, stream>>>(X, rows, cols, vals, AX, N_EDGES);
        dim3 g((N_NODES + 63) / 64, 256 / 64);
        gemm_xwt<true><<<g, 256, 0, stream>>>(AX, W, H, N_NODES);
    }
}

// Round 3
// 750.718 us; speedup vs baseline: 14.4650x; 1.4769x over previous
//
#include <hip/hip_runtime.h>
#include <hip/hip_bf16.h>

#define N_NODES 100000
#define N_EDGES 3200000
#define D 256

typedef __attribute__((ext_vector_type(8))) short short8;
typedef __attribute__((ext_vector_type(4))) float f32x4;

__device__ inline short bfbits(float x) {
    __hip_bfloat16 h = __float2bfloat16(x);
    return __builtin_bit_cast(short, h);
}

__device__ inline short8 load_cvt8(const float* __restrict__ p) {
    float4 a = *(const float4*)p;
    float4 b = *(const float4*)(p + 4);
    short8 r;
    r[0] = bfbits(a.x); r[1] = bfbits(a.y); r[2] = bfbits(a.z); r[3] = bfbits(a.w);
    r[4] = bfbits(b.x); r[5] = bfbits(b.y); r[6] = bfbits(b.z); r[7] = bfbits(b.w);
    return r;
}

// ============================ CSR construction =============================

__global__ __launch_bounds__(256) void edge_histogram(
    const int* __restrict__ rows, int* __restrict__ cnt, int nEdges)
{
    int e = blockIdx.x * 256 + threadIdx.x;
    if (e < nEdges) atomicAdd(&cnt[rows[e]], 1);
}

// Single-block scan, wave-shfl based (3 barriers per 4096-chunk).
// cnt may alias cursor: each index read only by the thread that later writes it.
__global__ __launch_bounds__(1024) void scan_rowptr(
    const int* __restrict__ cnt, int* __restrict__ row_ptr, int* __restrict__ cursor)
{
    __shared__ int wsum[16];
    __shared__ int wexcl[16];
    __shared__ int total_s;
    __shared__ int carry_s;
    const int t = threadIdx.x, lane = t & 63, wid = t >> 6;
    if (t == 0) carry_s = 0;
    for (int base = 0; base < N_NODES; base += 4096) {
        int i0 = base + t * 4;
        int x0 = 0, x1 = 0, x2 = 0, x3 = 0;
        if (i0 + 3 < N_NODES) {
            int4 q = *(const int4*)(cnt + i0);
            x0 = q.x; x1 = q.y; x2 = q.z; x3 = q.w;
        } else {
            if (i0     < N_NODES) x0 = cnt[i0];
            if (i0 + 1 < N_NODES) x1 = cnt[i0 + 1];
            if (i0 + 2 < N_NODES) x2 = cnt[i0 + 2];
        }
        int s = x0 + x1 + x2 + x3;
        int v = s;
        #pragma unroll
        for (int off = 1; off < 64; off <<= 1) {
            int u = __shfl_up(v, off);
            if (lane >= off) v += u;
        }
        if (lane == 63) wsum[wid] = v;
        __syncthreads();
        if (t < 16) {
            int p = 0;
            for (int j = 0; j < t; ++j) p += wsum[j];
            wexcl[t] = p;
            if (t == 15) total_s = p + wsum[15];
        }
        __syncthreads();
        int e0 = carry_s + wexcl[wid] + (v - s);
        if (i0     < N_NODES) { row_ptr[i0]     = e0;                 cursor[i0]     = e0; }
        if (i0 + 1 < N_NODES) { row_ptr[i0 + 1] = e0 + x0;            cursor[i0 + 1] = e0 + x0; }
        if (i0 + 2 < N_NODES) { row_ptr[i0 + 2] = e0 + x0 + x1;       cursor[i0 + 2] = e0 + x0 + x1; }
        if (i0 + 3 < N_NODES) { row_ptr[i0 + 3] = e0 + x0 + x1 + x2;  cursor[i0 + 3] = e0 + x0 + x1 + x2; }
        __syncthreads();
        if (t == 0) carry_s += total_s;
        __syncthreads();
    }
    if (t == 0) row_ptr[N_NODES] = carry_s;
}

__global__ __launch_bounds__(256) void edge_scatter(
    const int* __restrict__ rows, const int* __restrict__ cols,
    const float* __restrict__ vals, int* __restrict__ cursor,
    int2* __restrict__ cedge, int nEdges)
{
    int e = blockIdx.x * 256 + threadIdx.x;
    if (e >= nEdges) return;
    int p = atomicAdd(&cursor[rows[e]], 1);
    cedge[p] = make_int2(cols[e], __float_as_int(vals[e]));
}

// =================== GEMM: Y(bf16) = X @ W^T via MFMA ======================
// Block = 4 waves over the SAME 64 rows (X read once from HBM), wave w owns
// cols [64w, 64w+64). No LDS: frags loaded direct from global + cvt to bf16.
// mfma_f32_16x16x32_bf16 layouts (m89/m91-verified):
//   A: row = lane&15, k = (lane>>4)*8 + j   (8 consecutive k per lane)
//   B: col = lane&15, k = (lane>>4)*8 + j   (W[n][k] row-major is contiguous)
//   C/D: col = lane&15, row = (lane>>4)*4 + reg
__global__ __launch_bounds__(256) void gemm_bf16(
    const float* __restrict__ X,        // [M,256]
    const float* __restrict__ W,        // [256,256] row-major [out,in]
    unsigned short* __restrict__ Y,     // [M,256] bf16 out
    int M)
{
    const int wid  = threadIdx.x >> 6;
    const int lane = threadIdx.x & 63;
    const int m0   = blockIdx.x * 64;
    const int n0   = wid * 64;
    const int lr   = lane & 15;
    const int ko   = (lane >> 4) * 8;

    f32x4 acc[4][4] = {};

    #pragma unroll
    for (int k0 = 0; k0 < 256; k0 += 32) {
        short8 bfrag[4], afrag[4];
        #pragma unroll
        for (int j = 0; j < 4; ++j)
            bfrag[j] = load_cvt8(W + (size_t)(n0 + j * 16 + lr) * 256 + k0 + ko);
        #pragma unroll
        for (int i = 0; i < 4; ++i) {
            int r = m0 + i * 16 + lr;
            if (r > M - 1) r = M - 1;   // clamp; stores guarded below
            afrag[i] = load_cvt8(X + (size_t)r * 256 + k0 + ko);
        }
        #pragma unroll
        for (int i = 0; i < 4; ++i)
            #pragma unroll
            for (int j = 0; j < 4; ++j)
                acc[i][j] = __builtin_amdgcn_mfma_f32_16x16x32_bf16(
                    afrag[i], bfrag[j], acc[i][j], 0, 0, 0);
    }

    #pragma unroll
    for (int i = 0; i < 4; ++i) {
        int rbase = m0 + i * 16 + (lane >> 4) * 4;
        #pragma unroll
        for (int rr = 0; rr < 4; ++rr) {
            int r = rbase + rr;
            if (r < M) {
                #pragma unroll
                for (int j = 0; j < 4; ++j)
                    Y[(size_t)r * 256 + n0 + j * 16 + lr] =
                        (unsigned short)bfbits(acc[i][j][rr]);
            }
        }
    }
}

// ==================== Gather SpMM:  H = relu(A @ Y) ========================
// One wave per row. Lane l owns features [4l, 4l+4). Y is bf16 (512 B/row).
__global__ __launch_bounds__(256) void spmm_gather_relu(
    const unsigned short* __restrict__ Y,
    const int* __restrict__ row_ptr,
    const int2* __restrict__ cedge,
    float* __restrict__ H)
{
    int row  = blockIdx.x * 4 + (threadIdx.x >> 6);
    int lane = threadIdx.x & 63;
    if (row >= N_NODES) return;
    int s = row_ptr[row];
    int e = row_ptr[row + 1];

    float4 acc = make_float4(0.f, 0.f, 0.f, 0.f);
    for (int base = s; base < e; base += 64) {
        int idx = base + lane;
        int2 q = make_int2(0, 0);
        if (idx < e) q = cedge[idx];
        int cnt = min(64, e - base);
        for (int j = 0; j < cnt; ++j) {
            int   cj = __shfl(q.x, j);
            float vj = __int_as_float(__shfl(q.y, j));
            ushort4 y4 = *(const ushort4*)(Y + (size_t)cj * 256 + lane * 4);
            acc.x += __uint_as_float((unsigned)y4.x << 16) * vj;
            acc.y += __uint_as_float((unsigned)y4.y << 16) * vj;
            acc.z += __uint_as_float((unsigned)y4.z << 16) * vj;
            acc.w += __uint_as_float((unsigned)y4.w << 16) * vj;
        }
    }
    float4 r;
    r.x = acc.x > 0.f ? acc.x : 0.f;
    r.y = acc.y > 0.f ? acc.y : 0.f;
    r.z = acc.z > 0.f ? acc.z : 0.f;
    r.w = acc.w > 0.f ? acc.w : 0.f;
    ((float4*)(H + (size_t)row * 256))[lane] = r;
}

// ===========================================================================

extern "C" void kernel_launch(void* const* d_in, const int* in_sizes, int n_in,
                              void* d_out, int out_size, void* d_ws, size_t ws_size,
                              hipStream_t stream) {
    const float* X    = (const float*)d_in[0];
    const int*   rows = (const int*)d_in[1];
    const int*   cols = (const int*)d_in[2];
    const float* vals = (const float*)d_in[3];
    const float* W    = (const float*)d_in[4];
    float*       H    = (float*)d_out;

    // Workspace layout (all 256-aligned offsets):
    //   Y      : 51,200,000 B  (bf16 [N,256])
    //   row_ptr:    400,896 B  ((N+1)*4 padded)
    //   cursor :    400,896 B
    //   cedge  : 25,600,000 B  (int2 per edge)
    char* ws = (char*)d_ws;
    unsigned short* Y       = (unsigned short*)(ws);
    int*            row_ptr = (int*)(ws + 51200000);
    int*            cursor  = (int*)(ws + 51200000 + 400896);
    int2*           cedge   = (int2*)(ws + 51200000 + 2 * 400896);

    hipMemsetAsync(cursor, 0, (size_t)N_NODES * sizeof(int), stream);

    int eb = (N_EDGES + 255) / 256;
    edge_histogram<<<eb, 256, 0, stream>>>(rows, cursor, N_EDGES);
    scan_rowptr<<<1, 1024, 0, stream>>>(cursor, row_ptr, cursor);
    edge_scatter<<<eb, 256, 0, stream>>>(rows, cols, vals, cursor, cedge, N_EDGES);

    gemm_bf16<<<(N_NODES + 63) / 64, 256, 0, stream>>>(X, W, Y, N_NODES);

    spmm_gather_relu<<<(N_NODES + 3) / 4, 256, 0, stream>>>(Y, row_ptr, cedge, H);
}

// Round 4
// 484.986 us; speedup vs baseline: 22.3907x; 1.5479x over previous
//
#include <hip/hip_runtime.h>
#include <hip/hip_bf16.h>

#define N_NODES 100000
#define N_EDGES 3200000
#define D 256
#define SHIFT 9            // 512 rows per bucket
#define NB 196             // ceil(100000 / 512)
#define EPB 4096           // edges per bucket_split block

typedef __attribute__((ext_vector_type(8))) short short8;
typedef __attribute__((ext_vector_type(4))) float f32x4;

__device__ inline short bfbits(float x) {
    __hip_bfloat16 h = __float2bfloat16(x);
    return __builtin_bit_cast(short, h);
}

__device__ inline short8 load_cvt8(const float* __restrict__ p) {
    float4 a = *(const float4*)p;
    float4 b = *(const float4*)(p + 4);
    short8 r;
    r[0] = bfbits(a.x); r[1] = bfbits(a.y); r[2] = bfbits(a.z); r[3] = bfbits(a.w);
    r[4] = bfbits(b.x); r[5] = bfbits(b.y); r[6] = bfbits(b.z); r[7] = bfbits(b.w);
    return r;
}

// 256-thread block exclusive scan (wave shfl + 4 wave sums). wsum = LDS int[4].
__device__ inline int block_excl_scan_256(int c, int* wsum, int& total) {
    const int lane = threadIdx.x & 63, wid = threadIdx.x >> 6;
    int v = c;
    #pragma unroll
    for (int off = 1; off < 64; off <<= 1) {
        int u = __shfl_up(v, off);
        if (lane >= off) v += u;
    }
    if (lane == 63) wsum[wid] = v;
    __syncthreads();
    int w0 = wsum[0], w1 = wsum[1], w2 = wsum[2], w3 = wsum[3];
    total = w0 + w1 + w2 + w3;
    int wex = (wid > 0 ? w0 : 0) + (wid > 1 ? w1 : 0) + (wid > 2 ? w2 : 0);
    return wex + v - c;
}

// ===================== 1) global bucket histogram (LDS-staged) =============
__global__ __launch_bounds__(256) void bucket_hist(
    const int* __restrict__ rows, int* __restrict__ gcnt, int nE)
{
    __shared__ int h[NB];
    for (int i = threadIdx.x; i < NB; i += 256) h[i] = 0;
    __syncthreads();
    for (int e = blockIdx.x * 256 + threadIdx.x; e < nE; e += gridDim.x * 256)
        atomicAdd(&h[rows[e] >> SHIFT], 1);
    __syncthreads();
    for (int i = threadIdx.x; i < NB; i += 256)
        if (h[i]) atomicAdd(&gcnt[i], h[i]);
}

// ===================== 2) bucket scan (one block) ==========================
__global__ __launch_bounds__(256) void bucket_scan(
    const int* __restrict__ gcnt, int* __restrict__ bbase,
    int* __restrict__ gcursor, int* __restrict__ row_ptr)
{
    __shared__ int wsum[4];
    int c = (threadIdx.x < NB) ? gcnt[threadIdx.x] : 0;
    int total;
    int ex = block_excl_scan_256(c, wsum, total);
    if (threadIdx.x < NB) { bbase[threadIdx.x] = ex; gcursor[threadIdx.x] = ex; }
    if (threadIdx.x == 0) { bbase[NB] = total; row_ptr[N_NODES] = total; }
}

// ===================== 3) bucket split (LDS-staged scatter) ================
// Block handles EPB contiguous edges; stages them bucket-grouped in LDS, then
// copies each bucket's chunk out as one dense coalesced burst.
__global__ __launch_bounds__(256) void bucket_split(
    const int* __restrict__ rows, const int* __restrict__ cols,
    const float* __restrict__ vals, int* __restrict__ gcursor,
    int* __restrict__ brow, int2* __restrict__ bcv, int nE)
{
    __shared__ int cnt[256];
    __shared__ int startp[256];
    __shared__ int posp[256];
    __shared__ int gb[256];
    __shared__ int wsum[4];
    __shared__ int srow[EPB];
    __shared__ int2 scv[EPB];
    const int t  = threadIdx.x;
    const int e0 = blockIdx.x * EPB;

    cnt[t] = 0;
    __syncthreads();

    int   myrow[16];
    int   mycol[16];
    float myval[16];
    #pragma unroll
    for (int k = 0; k < 16; ++k) {
        int e = e0 + k * 256 + t;
        if (e < nE) {
            myrow[k] = rows[e]; mycol[k] = cols[e]; myval[k] = vals[e];
            atomicAdd(&cnt[myrow[k] >> SHIFT], 1);
        } else {
            myrow[k] = -1; mycol[k] = 0; myval[k] = 0.f;
        }
    }
    __syncthreads();

    int c = cnt[t];
    int total;
    int ex = block_excl_scan_256(c, wsum, total);
    startp[t] = ex;
    posp[t]   = ex;
    if (t < NB && c) gb[t] = atomicAdd(&gcursor[t], c);
    __syncthreads();

    #pragma unroll
    for (int k = 0; k < 16; ++k) {
        if (myrow[k] >= 0) {
            int b = myrow[k] >> SHIFT;
            int p = atomicAdd(&posp[b], 1);
            srow[p] = myrow[k];
            scv[p]  = make_int2(mycol[k], __float_as_int(myval[k]));
        }
    }
    __syncthreads();

    const int lane = t & 63, wid = t >> 6;
    for (int b = wid; b < NB; b += 4) {
        int cb = cnt[b];
        if (!cb) continue;
        int st = startp[b], g = gb[b];
        for (int i = lane; i < cb; i += 64) {
            brow[g + i] = srow[st + i];
            bcv[g + i]  = scv[st + i];
        }
    }
}

// ===================== 4) per-bucket counting sort -> CSR ==================
// One block per bucket (512 rows). Writes row_ptr and row-sorted cedge.
__global__ __launch_bounds__(256) void bucket_to_csr(
    const int* __restrict__ bbase, const int* __restrict__ brow,
    const int2* __restrict__ bcv, int* __restrict__ row_ptr,
    int2* __restrict__ cedge)
{
    __shared__ int hist[512];
    __shared__ int cur[512];
    __shared__ int wsum[4];
    const int t  = threadIdx.x;
    const int b  = blockIdx.x;
    const int r0 = b << SHIFT;
    const int s  = bbase[b], e = bbase[b + 1];

    hist[t] = 0; hist[t + 256] = 0;
    __syncthreads();
    for (int j = s + t; j < e; j += 256)
        atomicAdd(&hist[brow[j] - r0], 1);
    __syncthreads();

    int c0 = hist[2 * t], c1 = hist[2 * t + 1];
    int total;
    int ex = block_excl_scan_256(c0 + c1, wsum, total);
    cur[2 * t]     = s + ex;
    cur[2 * t + 1] = s + ex + c0;
    int r = r0 + 2 * t;
    if (r     < N_NODES) row_ptr[r]     = s + ex;
    if (r + 1 < N_NODES) row_ptr[r + 1] = s + ex + c0;
    __syncthreads();

    for (int j = s + t; j < e; j += 256) {
        int rr = brow[j];
        int p = atomicAdd(&cur[rr - r0], 1);
        cedge[p] = bcv[j];
    }
}

// =================== 5) GEMM: Y(bf16) = X @ W^T via MFMA ===================
__global__ __launch_bounds__(256) void gemm_bf16(
    const float* __restrict__ X,        // [M,256]
    const float* __restrict__ W,        // [256,256] row-major [out,in]
    unsigned short* __restrict__ Y,     // [M,256] bf16 out
    int M)
{
    const int wid  = threadIdx.x >> 6;
    const int lane = threadIdx.x & 63;
    const int m0   = blockIdx.x * 64;
    const int n0   = wid * 64;
    const int lr   = lane & 15;
    const int ko   = (lane >> 4) * 8;

    f32x4 acc[4][4] = {};

    #pragma unroll
    for (int k0 = 0; k0 < 256; k0 += 32) {
        short8 bfrag[4], afrag[4];
        #pragma unroll
        for (int j = 0; j < 4; ++j)
            bfrag[j] = load_cvt8(W + (size_t)(n0 + j * 16 + lr) * 256 + k0 + ko);
        #pragma unroll
        for (int i = 0; i < 4; ++i) {
            int r = m0 + i * 16 + lr;
            if (r > M - 1) r = M - 1;
            afrag[i] = load_cvt8(X + (size_t)r * 256 + k0 + ko);
        }
        #pragma unroll
        for (int i = 0; i < 4; ++i)
            #pragma unroll
            for (int j = 0; j < 4; ++j)
                acc[i][j] = __builtin_amdgcn_mfma_f32_16x16x32_bf16(
                    afrag[i], bfrag[j], acc[i][j], 0, 0, 0);
    }

    #pragma unroll
    for (int i = 0; i < 4; ++i) {
        int rbase = m0 + i * 16 + (lane >> 4) * 4;
        #pragma unroll
        for (int rr = 0; rr < 4; ++rr) {
            int r = rbase + rr;
            if (r < M) {
                #pragma unroll
                for (int j = 0; j < 4; ++j)
                    Y[(size_t)r * 256 + n0 + j * 16 + lr] =
                        (unsigned short)bfbits(acc[i][j][rr]);
            }
        }
    }
}

// =================== 6) Gather SpMM:  H = relu(A @ Y) ======================
__global__ __launch_bounds__(256) void spmm_gather_relu(
    const unsigned short* __restrict__ Y,
    const int* __restrict__ row_ptr,
    const int2* __restrict__ cedge,
    float* __restrict__ H)
{
    int row  = blockIdx.x * 4 + (threadIdx.x >> 6);
    int lane = threadIdx.x & 63;
    if (row >= N_NODES) return;
    int s = row_ptr[row];
    int e = row_ptr[row + 1];

    float4 acc = make_float4(0.f, 0.f, 0.f, 0.f);
    for (int base = s; base < e; base += 64) {
        int idx = base + lane;
        int2 q = make_int2(0, 0);
        if (idx < e) q = cedge[idx];
        int cnt = min(64, e - base);
        for (int j = 0; j < cnt; ++j) {
            int   cj = __shfl(q.x, j);
            float vj = __int_as_float(__shfl(q.y, j));
            ushort4 y4 = *(const ushort4*)(Y + (size_t)cj * 256 + lane * 4);
            acc.x += __uint_as_float((unsigned)y4.x << 16) * vj;
            acc.y += __uint_as_float((unsigned)y4.y << 16) * vj;
            acc.z += __uint_as_float((unsigned)y4.z << 16) * vj;
            acc.w += __uint_as_float((unsigned)y4.w << 16) * vj;
        }
    }
    float4 r;
    r.x = acc.x > 0.f ? acc.x : 0.f;
    r.y = acc.y > 0.f ? acc.y : 0.f;
    r.z = acc.z > 0.f ? acc.z : 0.f;
    r.w = acc.w > 0.f ? acc.w : 0.f;
    ((float4*)(H + (size_t)row * 256))[lane] = r;
}

// ===========================================================================

extern "C" void kernel_launch(void* const* d_in, const int* in_sizes, int n_in,
                              void* d_out, int out_size, void* d_ws, size_t ws_size,
                              hipStream_t stream) {
    const float* X    = (const float*)d_in[0];
    const int*   rows = (const int*)d_in[1];
    const int*   cols = (const int*)d_in[2];
    const float* vals = (const float*)d_in[3];
    const float* W    = (const float*)d_in[4];
    float*       H    = (float*)d_out;

    // Workspace layout (256-aligned):
    //   Y       @          0 : 51,200,000  bf16 [N,256]
    //   row_ptr @ 51,200,000 :    400,896  int [N+1]
    //   cedge   @ 51,600,896 : 25,600,000  int2 [E]  (row-sorted col,val)
    //   brow    @ 77,200,896 : 12,800,000  int  [E]  (bucket-split rows)
    //   bcv     @ 90,000,896 : 25,600,000  int2 [E]  (bucket-split col,val)
    //   gcnt    @115,600,896 :      1,024  int [NB]
    //   bbase   @115,601,920 :      1,024  int [NB+1]
    //   gcursor @115,602,944 :      1,024  int [NB]
    char* ws = (char*)d_ws;
    unsigned short* Y       = (unsigned short*)(ws);
    int*            row_ptr = (int*)(ws + 51200000);
    int2*           cedge   = (int2*)(ws + 51600896);
    int*            brow    = (int*)(ws + 77200896);
    int2*           bcv     = (int2*)(ws + 90000896);
    int*            gcnt    = (int*)(ws + 115600896);
    int*            bbase   = (int*)(ws + 115601920);
    int*            gcursor = (int*)(ws + 115602944);

    hipMemsetAsync(gcnt, 0, NB * sizeof(int), stream);

    bucket_hist<<<256, 256, 0, stream>>>(rows, gcnt, N_EDGES);
    bucket_scan<<<1, 256, 0, stream>>>(gcnt, bbase, gcursor, row_ptr);
    bucket_split<<<(N_EDGES + EPB - 1) / EPB, 256, 0, stream>>>(
        rows, cols, vals, gcursor, brow, bcv, N_EDGES);
    bucket_to_csr<<<NB, 256, 0, stream>>>(bbase, brow, bcv, row_ptr, cedge);

    gemm_bf16<<<(N_NODES + 63) / 64, 256, 0, stream>>>(X, W, Y, N_NODES);

    spmm_gather_relu<<<(N_NODES + 3) / 4, 256, 0, stream>>>(Y, row_ptr, cedge, H);
}

// Round 5
// 451.204 us; speedup vs baseline: 24.0670x; 1.0749x over previous
//
#include <hip/hip_runtime.h>
#include <hip/hip_bf16.h>

#define N_NODES 100000
#define N_EDGES 3200000
#define D 256
#define SHIFT 9            // 512 rows per bucket
#define NB 196             // ceil(100000 / 512)
#define EPB 4096           // edges per bucket_split block

typedef __attribute__((ext_vector_type(8))) short short8;
typedef __attribute__((ext_vector_type(4))) float f32x4;

__device__ inline short bfbits(float x) {
    __hip_bfloat16 h = __float2bfloat16(x);
    return __builtin_bit_cast(short, h);
}

__device__ inline short8 load_cvt8(const float* __restrict__ p) {
    float4 a = *(const float4*)p;
    float4 b = *(const float4*)(p + 4);
    short8 r;
    r[0] = bfbits(a.x); r[1] = bfbits(a.y); r[2] = bfbits(a.z); r[3] = bfbits(a.w);
    r[4] = bfbits(b.x); r[5] = bfbits(b.y); r[6] = bfbits(b.z); r[7] = bfbits(b.w);
    return r;
}

// 256-thread block exclusive scan (wave shfl + 4 wave sums). wsum = LDS int[4].
__device__ inline int block_excl_scan_256(int c, int* wsum, int& total) {
    const int lane = threadIdx.x & 63, wid = threadIdx.x >> 6;
    int v = c;
    #pragma unroll
    for (int off = 1; off < 64; off <<= 1) {
        int u = __shfl_up(v, off);
        if (lane >= off) v += u;
    }
    if (lane == 63) wsum[wid] = v;
    __syncthreads();
    int w0 = wsum[0], w1 = wsum[1], w2 = wsum[2], w3 = wsum[3];
    total = w0 + w1 + w2 + w3;
    int wex = (wid > 0 ? w0 : 0) + (wid > 1 ? w1 : 0) + (wid > 2 ? w2 : 0);
    return wex + v - c;
}

// ===================== 1) global bucket histogram (LDS-staged) =============
__global__ __launch_bounds__(256) void bucket_hist(
    const int* __restrict__ rows, int* __restrict__ gcnt, int nE)
{
    __shared__ int h[NB];
    for (int i = threadIdx.x; i < NB; i += 256) h[i] = 0;
    __syncthreads();
    for (int e = blockIdx.x * 256 + threadIdx.x; e < nE; e += gridDim.x * 256)
        atomicAdd(&h[rows[e] >> SHIFT], 1);
    __syncthreads();
    for (int i = threadIdx.x; i < NB; i += 256)
        if (h[i]) atomicAdd(&gcnt[i], h[i]);
}

// ===================== 2) bucket scan (one block) ==========================
__global__ __launch_bounds__(256) void bucket_scan(
    const int* __restrict__ gcnt, int* __restrict__ bbase,
    int* __restrict__ gcursor, int* __restrict__ row_ptr)
{
    __shared__ int wsum[4];
    int c = (threadIdx.x < NB) ? gcnt[threadIdx.x] : 0;
    int total;
    int ex = block_excl_scan_256(c, wsum, total);
    if (threadIdx.x < NB) { bbase[threadIdx.x] = ex; gcursor[threadIdx.x] = ex; }
    if (threadIdx.x == 0) { bbase[NB] = total; row_ptr[N_NODES] = total; }
}

// ===================== 3) bucket split (LDS-staged scatter) ================
// Payload packed: pk.x = (row_local<<17) | col  (row_local 9b, col 17b),
// pk.y = fp32 val bits. One 8 B element per edge.
__global__ __launch_bounds__(256) void bucket_split(
    const int* __restrict__ rows, const int* __restrict__ cols,
    const float* __restrict__ vals, int* __restrict__ gcursor,
    int2* __restrict__ bcv, int nE)
{
    __shared__ int cnt[256];
    __shared__ int startp[256];
    __shared__ int posp[256];
    __shared__ int gb[256];
    __shared__ int wsum[4];
    __shared__ int2 scv[EPB];
    const int t  = threadIdx.x;
    const int e0 = blockIdx.x * EPB;

    cnt[t] = 0;
    __syncthreads();

    int   myrow[16];
    int   mycol[16];
    float myval[16];
    #pragma unroll
    for (int k = 0; k < 16; ++k) {
        int e = e0 + k * 256 + t;
        if (e < nE) {
            myrow[k] = rows[e]; mycol[k] = cols[e]; myval[k] = vals[e];
            atomicAdd(&cnt[myrow[k] >> SHIFT], 1);
        } else {
            myrow[k] = -1; mycol[k] = 0; myval[k] = 0.f;
        }
    }
    __syncthreads();

    int c = cnt[t];
    int total;
    int ex = block_excl_scan_256(c, wsum, total);
    startp[t] = ex;
    posp[t]   = ex;
    if (t < NB && c) gb[t] = atomicAdd(&gcursor[t], c);
    __syncthreads();

    #pragma unroll
    for (int k = 0; k < 16; ++k) {
        if (myrow[k] >= 0) {
            int b = myrow[k] >> SHIFT;
            int p = atomicAdd(&posp[b], 1);
            scv[p] = make_int2(((myrow[k] & 511) << 17) | mycol[k],
                               __float_as_int(myval[k]));
        }
    }
    __syncthreads();

    const int lane = t & 63, wid = t >> 6;
    for (int b = wid; b < NB; b += 4) {
        int cb = cnt[b];
        if (!cb) continue;
        int st = startp[b], g = gb[b];
        for (int i = lane; i < cb; i += 64)
            bcv[g + i] = scv[st + i];
    }
}

// ===================== 4) per-bucket counting sort -> CSR ==================
// One block per bucket (512 rows). Bucket data (~16K x 8 B = 131 KB) stays
// L2-resident between the two passes.
__global__ __launch_bounds__(256) void bucket_to_csr(
    const int* __restrict__ bbase, const int2* __restrict__ bcv,
    int* __restrict__ row_ptr, int2* __restrict__ cedge)
{
    __shared__ int hist[512];
    __shared__ int cur[512];
    __shared__ int wsum[4];
    const int t  = threadIdx.x;
    const int b  = blockIdx.x;
    const int r0 = b << SHIFT;
    const int s  = bbase[b], e = bbase[b + 1];

    hist[t] = 0; hist[t + 256] = 0;
    __syncthreads();
    for (int j = s + t; j < e; j += 256)
        atomicAdd(&hist[(unsigned)bcv[j].x >> 17], 1);
    __syncthreads();

    int c0 = hist[2 * t], c1 = hist[2 * t + 1];
    int total;
    int ex = block_excl_scan_256(c0 + c1, wsum, total);
    cur[2 * t]     = s + ex;
    cur[2 * t + 1] = s + ex + c0;
    int r = r0 + 2 * t;
    if (r     < N_NODES) row_ptr[r]     = s + ex;
    if (r + 1 < N_NODES) row_ptr[r + 1] = s + ex + c0;
    __syncthreads();

    for (int j = s + t; j < e; j += 256) {
        int2 q = bcv[j];
        int rl = (unsigned)q.x >> 17;
        int p = atomicAdd(&cur[rl], 1);
        cedge[p] = make_int2(q.x & 0x1FFFF, q.y);
    }
}

// =================== 5) GEMM: Y(bf16) = X @ W^T via MFMA ===================
__global__ __launch_bounds__(256) void gemm_bf16(
    const float* __restrict__ X,        // [M,256]
    const float* __restrict__ W,        // [256,256] row-major [out,in]
    unsigned short* __restrict__ Y,     // [M,256] bf16 out
    int M)
{
    const int wid  = threadIdx.x >> 6;
    const int lane = threadIdx.x & 63;
    const int m0   = blockIdx.x * 64;
    const int n0   = wid * 64;
    const int lr   = lane & 15;
    const int ko   = (lane >> 4) * 8;

    f32x4 acc[4][4] = {};

    #pragma unroll
    for (int k0 = 0; k0 < 256; k0 += 32) {
        short8 bfrag[4], afrag[4];
        #pragma unroll
        for (int j = 0; j < 4; ++j)
            bfrag[j] = load_cvt8(W + (size_t)(n0 + j * 16 + lr) * 256 + k0 + ko);
        #pragma unroll
        for (int i = 0; i < 4; ++i) {
            int r = m0 + i * 16 + lr;
            if (r > M - 1) r = M - 1;
            afrag[i] = load_cvt8(X + (size_t)r * 256 + k0 + ko);
        }
        #pragma unroll
        for (int i = 0; i < 4; ++i)
            #pragma unroll
            for (int j = 0; j < 4; ++j)
                acc[i][j] = __builtin_amdgcn_mfma_f32_16x16x32_bf16(
                    afrag[i], bfrag[j], acc[i][j], 0, 0, 0);
    }

    #pragma unroll
    for (int i = 0; i < 4; ++i) {
        int rbase = m0 + i * 16 + (lane >> 4) * 4;
        #pragma unroll
        for (int rr = 0; rr < 4; ++rr) {
            int r = rbase + rr;
            if (r < M) {
                #pragma unroll
                for (int j = 0; j < 4; ++j)
                    Y[(size_t)r * 256 + n0 + j * 16 + lr] =
                        (unsigned short)bfbits(acc[i][j][rr]);
            }
        }
    }
}

// =================== 6) Gather SpMM:  H = relu(A @ Y) ======================
// One wave per row; lane l owns features [4l,4l+4). 4-wide edge unroll for
// memory-level parallelism; scalar (readfirstlane) row bases.
__global__ __launch_bounds__(256) void spmm_gather_relu(
    const unsigned short* __restrict__ Y,
    const int* __restrict__ row_ptr,
    const int2* __restrict__ cedge,
    float* __restrict__ H)
{
    int row  = blockIdx.x * 4 + (threadIdx.x >> 6);
    int lane = threadIdx.x & 63;
    if (row >= N_NODES) return;
    int s = row_ptr[row];
    int e = row_ptr[row + 1];

    float4 acc = make_float4(0.f, 0.f, 0.f, 0.f);
    const int fo = lane * 4;   // ushort offset within row

    for (int base = s; base < e; base += 64) {
        int idx = base + lane;
        int2 q = make_int2(0, 0);
        if (idx < e) q = cedge[idx];
        int cnt = min(64, e - base);
        int j = 0;
        for (; j + 4 <= cnt; j += 4) {
            int c0 = __builtin_amdgcn_readfirstlane(__shfl(q.x, j));
            int c1 = __builtin_amdgcn_readfirstlane(__shfl(q.x, j + 1));
            int c2 = __builtin_amdgcn_readfirstlane(__shfl(q.x, j + 2));
            int c3 = __builtin_amdgcn_readfirstlane(__shfl(q.x, j + 3));
            float v0 = __int_as_float(__builtin_amdgcn_readfirstlane(__shfl(q.y, j)));
            float v1 = __int_as_float(__builtin_amdgcn_readfirstlane(__shfl(q.y, j + 1)));
            float v2 = __int_as_float(__builtin_amdgcn_readfirstlane(__shfl(q.y, j + 2)));
            float v3 = __int_as_float(__builtin_amdgcn_readfirstlane(__shfl(q.y, j + 3)));
            ushort4 y0 = *(const ushort4*)(Y + (size_t)c0 * 256 + fo);
            ushort4 y1 = *(const ushort4*)(Y + (size_t)c1 * 256 + fo);
            ushort4 y2 = *(const ushort4*)(Y + (size_t)c2 * 256 + fo);
            ushort4 y3 = *(const ushort4*)(Y + (size_t)c3 * 256 + fo);
            acc.x += __uint_as_float((unsigned)y0.x << 16) * v0;
            acc.y += __uint_as_float((unsigned)y0.y << 16) * v0;
            acc.z += __uint_as_float((unsigned)y0.z << 16) * v0;
            acc.w += __uint_as_float((unsigned)y0.w << 16) * v0;
            acc.x += __uint_as_float((unsigned)y1.x << 16) * v1;
            acc.y += __uint_as_float((unsigned)y1.y << 16) * v1;
            acc.z += __uint_as_float((unsigned)y1.z << 16) * v1;
            acc.w += __uint_as_float((unsigned)y1.w << 16) * v1;
            acc.x += __uint_as_float((unsigned)y2.x << 16) * v2;
            acc.y += __uint_as_float((unsigned)y2.y << 16) * v2;
            acc.z += __uint_as_float((unsigned)y2.z << 16) * v2;
            acc.w += __uint_as_float((unsigned)y2.w << 16) * v2;
            acc.x += __uint_as_float((unsigned)y3.x << 16) * v3;
            acc.y += __uint_as_float((unsigned)y3.y << 16) * v3;
            acc.z += __uint_as_float((unsigned)y3.z << 16) * v3;
            acc.w += __uint_as_float((unsigned)y3.w << 16) * v3;
        }
        for (; j < cnt; ++j) {
            int   cj = __builtin_amdgcn_readfirstlane(__shfl(q.x, j));
            float vj = __int_as_float(__builtin_amdgcn_readfirstlane(__shfl(q.y, j)));
            ushort4 y4 = *(const ushort4*)(Y + (size_t)cj * 256 + fo);
            acc.x += __uint_as_float((unsigned)y4.x << 16) * vj;
            acc.y += __uint_as_float((unsigned)y4.y << 16) * vj;
            acc.z += __uint_as_float((unsigned)y4.z << 16) * vj;
            acc.w += __uint_as_float((unsigned)y4.w << 16) * vj;
        }
    }
    float4 r;
    r.x = acc.x > 0.f ? acc.x : 0.f;
    r.y = acc.y > 0.f ? acc.y : 0.f;
    r.z = acc.z > 0.f ? acc.z : 0.f;
    r.w = acc.w > 0.f ? acc.w : 0.f;
    ((float4*)(H + (size_t)row * 256))[lane] = r;
}

// ===========================================================================

extern "C" void kernel_launch(void* const* d_in, const int* in_sizes, int n_in,
                              void* d_out, int out_size, void* d_ws, size_t ws_size,
                              hipStream_t stream) {
    const float* X    = (const float*)d_in[0];
    const int*   rows = (const int*)d_in[1];
    const int*   cols = (const int*)d_in[2];
    const float* vals = (const float*)d_in[3];
    const float* W    = (const float*)d_in[4];
    float*       H    = (float*)d_out;

    // Workspace layout (256-aligned):
    //   Y       @          0 : 51,200,000  bf16 [N,256]
    //   row_ptr @ 51,200,000 :    400,896  int [N+1]
    //   cedge   @ 51,600,896 : 25,600,000  int2 [E]  (row-sorted col,val)
    //   bcv     @ 77,200,896 : 25,600,000  int2 [E]  (bucket-split packed)
    //   gcnt    @102,800,896 :      1,024  int [NB]
    //   bbase   @102,801,920 :      1,024  int [NB+1]
    //   gcursor @102,802,944 :      1,024  int [NB]
    char* ws = (char*)d_ws;
    unsigned short* Y       = (unsigned short*)(ws);
    int*            row_ptr = (int*)(ws + 51200000);
    int2*           cedge   = (int2*)(ws + 51600896);
    int2*           bcv     = (int2*)(ws + 77200896);
    int*            gcnt    = (int*)(ws + 102800896);
    int*            bbase   = (int*)(ws + 102801920);
    int*            gcursor = (int*)(ws + 102802944);

    hipMemsetAsync(gcnt, 0, NB * sizeof(int), stream);

    bucket_hist<<<256, 256, 0, stream>>>(rows, gcnt, N_EDGES);
    bucket_scan<<<1, 256, 0, stream>>>(gcnt, bbase, gcursor, row_ptr);
    bucket_split<<<(N_EDGES + EPB - 1) / EPB, 256, 0, stream>>>(
        rows, cols, vals, gcursor, bcv, N_EDGES);
    bucket_to_csr<<<NB, 256, 0, stream>>>(bbase, bcv, row_ptr, cedge);

    gemm_bf16<<<(N_NODES + 63) / 64, 256, 0, stream>>>(X, W, Y, N_NODES);

    spmm_gather_relu<<<(N_NODES + 3) / 4, 256, 0, stream>>>(Y, row_ptr, cedge, H);
}